// Round 8
// baseline (58.198 us; speedup 1.0000x reference)
//
#include <hip/hip_runtime.h>

#define D 8192
#define T_STEPS 100
#define SPIKE_THR 0.5f
#define BLOCK 256
#define WAVES (BLOCK / 64)
#define COLS_PER_THREAD 4
#define NCHUNK 256
#define ROWS_PER_CHUNK (D / NCHUNK)                    // 32
#define COLBLOCKS (D / (BLOCK * COLS_PER_THREAD))      // 8
#define NABS (NCHUNK * COLBLOCKS * WAVES)              // 8192 partials

#define RED_COLS 256                                   // cols per fused block
#define RED_SEGS 4                                     // waves per block
#define RED_BLOCKS (D / RED_COLS)                      // 32
#define CHUNKS_PER_SEG (NCHUNK / RED_SEGS)             // 64
#define STEPS_PER_SEG (T_STEPS / RED_SEGS)             // 25

// Kernel 1: partial column-dot-products over a 32-row chunk + partial sum(|W|).
// grid = (COLBLOCKS, NCHUNK) = (8, 256) = 2048 blocks (exactly co-resident).
// x is read via wave-uniform scalar loads (no LDS, no barrier).
__global__ void __launch_bounds__(BLOCK)
k_partial(const float* __restrict__ x, const float* __restrict__ W,
          float* __restrict__ ws_drive, float* __restrict__ ws_abs) {
    const int chunk = blockIdx.y;
    const int row0  = chunk * ROWS_PER_CHUNK;
    const int j0 = (blockIdx.x * BLOCK + threadIdx.x) * COLS_PER_THREAD;

    float ax = 0.f, ay = 0.f, az = 0.f, aw = 0.f;
    float asum = 0.f;
    #pragma unroll 8
    for (int i = 0; i < ROWS_PER_CHUNK; ++i) {
        const float xv = x[row0 + i];   // uniform -> s_load, K$-cached
        const float4 w = *reinterpret_cast<const float4*>(
            &W[(size_t)(row0 + i) * D + j0]);
        ax = fmaf(xv, w.x, ax);
        ay = fmaf(xv, w.y, ay);
        az = fmaf(xv, w.z, az);
        aw = fmaf(xv, w.w, aw);
        asum += fabsf(w.x) + fabsf(w.y) + fabsf(w.z) + fabsf(w.w);
    }

    float4 acc; acc.x = ax; acc.y = ay; acc.z = az; acc.w = aw;
    *reinterpret_cast<float4*>(&ws_drive[(size_t)chunk * D + j0]) = acc;

    // per-wave butterfly reduce of |W| partial (register-only, no barriers)
    #pragma unroll
    for (int off = 32; off > 0; off >>= 1)
        asum += __shfl_down(asum, off, 64);
    if ((threadIdx.x & 63) == 0)
        ws_abs[(chunk * COLBLOCKS + blockIdx.x) * WAVES + (threadIdx.x >> 6)] = asum;
}

// Kernel 2 (fused): reduce ws_drive -> drive for 256 cols, then simulate.
// grid = RED_BLOCKS + 1 = 33, block = 256 = 4 waves.
// Thread (seg, lane) owns a float4 of columns; its wave's loads/stores are
// 1 KB contiguous. Wave `seg` sums 64 chunks, LDS-combines, warms up seg*25
// steps in registers, then stores its 25 timesteps.
// Block 32 reduces ws_abs -> activity scalar at out[2*T*D].
__global__ void __launch_bounds__(BLOCK)
k_fused(const float* __restrict__ ws_drive, const float* __restrict__ ws_abs,
        const float* __restrict__ pot0, float* __restrict__ out) {
    if (blockIdx.x == RED_BLOCKS) {
        __shared__ float red[BLOCK];
        float s = 0.f;
        for (int i = threadIdx.x; i < NABS; i += BLOCK) s += ws_abs[i];
        red[threadIdx.x] = s;
        __syncthreads();
        for (int st = BLOCK / 2; st > 0; st >>= 1) {
            if (threadIdx.x < st) red[threadIdx.x] += red[threadIdx.x + st];
            __syncthreads();
        }
        if (threadIdx.x == 0)
            out[(size_t)2 * T_STEPS * D] = red[0] / ((float)D * (float)D);
        return;
    }

    __shared__ float4 part[RED_SEGS][64];
    const int lane = threadIdx.x & 63;
    const int seg  = threadIdx.x >> 6;                 // wave id, 0..3
    const int j0   = blockIdx.x * RED_COLS + lane * 4;

    // each wave sums a 64-chunk segment for its float4 of columns
    float sx = 0.f, sy = 0.f, sz = 0.f, sw = 0.f;
    const int c0 = seg * CHUNKS_PER_SEG;
    #pragma unroll 8
    for (int cc = 0; cc < CHUNKS_PER_SEG; ++cc) {
        const float4 p = *reinterpret_cast<const float4*>(
            &ws_drive[(size_t)(c0 + cc) * D + j0]);
        sx += p.x; sy += p.y; sz += p.z; sw += p.w;
    }
    float4 a; a.x = sx; a.y = sy; a.z = sz; a.w = sw;
    part[seg][lane] = a;
    __syncthreads();

    const float4 d0 = part[0][lane], d1 = part[1][lane],
                 d2 = part[2][lane], d3 = part[3][lane];
    float dx = d0.x + d1.x + d2.x + d3.x;
    float dy = d0.y + d1.y + d2.y + d3.y;
    float dz = d0.z + d1.z + d2.z + d3.z;
    float dw = d0.w + d1.w + d2.w + d3.w;

    const float4 p0 = *reinterpret_cast<const float4*>(&pot0[j0]);
    float px = p0.x, py = p0.y, pz = p0.z, pw = p0.w;

    // warm up to this wave's time slice (register-only)
    const int t0 = seg * STEPS_PER_SEG;
    for (int t = 0; t < t0; ++t) {
        px += dx; py += dy; pz += dz; pw += dw;
        px = (px >= SPIKE_THR) ? 0.f : px;
        py = (py >= SPIKE_THR) ? 0.f : py;
        pz = (pz >= SPIKE_THR) ? 0.f : pz;
        pw = (pw >= SPIKE_THR) ? 0.f : pw;
    }

    float* __restrict__ spikes = out;
    float* __restrict__ pots   = out + (size_t)T_STEPS * D;

    #pragma unroll
    for (int s2 = 0; s2 < STEPS_PER_SEG; ++s2) {
        const int t = t0 + s2;
        px += dx; py += dy; pz += dz; pw += dw;
        float4 sp;
        sp.x = (px >= SPIKE_THR) ? 1.f : 0.f;
        sp.y = (py >= SPIKE_THR) ? 1.f : 0.f;
        sp.z = (pz >= SPIKE_THR) ? 1.f : 0.f;
        sp.w = (pw >= SPIKE_THR) ? 1.f : 0.f;
        px *= (1.f - sp.x); py *= (1.f - sp.y);
        pz *= (1.f - sp.z); pw *= (1.f - sp.w);
        *reinterpret_cast<float4*>(&spikes[(size_t)t * D + j0]) = sp;
        float4 pv; pv.x = px; pv.y = py; pv.z = pz; pv.w = pw;
        *reinterpret_cast<float4*>(&pots[(size_t)t * D + j0]) = pv;
    }
}

extern "C" void kernel_launch(void* const* d_in, const int* in_sizes, int n_in,
                              void* d_out, int out_size, void* d_ws, size_t ws_size,
                              hipStream_t stream) {
    const float* x   = (const float*)d_in[0];
    const float* W   = (const float*)d_in[1];
    const float* mp0 = (const float*)d_in[2];
    float* out = (float*)d_out;

    float* ws_drive = (float*)d_ws;                       // NCHUNK*D floats = 8 MiB
    float* ws_abs   = ws_drive + (size_t)NCHUNK * D;      // NABS floats

    dim3 g1(COLBLOCKS, NCHUNK);
    k_partial<<<g1, BLOCK, 0, stream>>>(x, W, ws_drive, ws_abs);
    k_fused<<<RED_BLOCKS + 1, BLOCK, 0, stream>>>(ws_drive, ws_abs, mp0, out);
}

// Round 9
// 55.616 us; speedup vs baseline: 1.0464x; 1.0464x over previous
//
#include <hip/hip_runtime.h>

#define D 8192
#define T_STEPS 100
#define SPIKE_THR 0.5f
#define BLOCK 256
#define WAVES (BLOCK / 64)
#define COLS_PER_THREAD 4
#define NCHUNK 256
#define ROWS_PER_CHUNK (D / NCHUNK)                    // 32
#define COLBLOCKS (D / (BLOCK * COLS_PER_THREAD))      // 8
#define NABS (NCHUNK * COLBLOCKS * WAVES)              // 8192 partials

#define RED_COLS 64                                    // cols per fused block
#define RED_SEGS (BLOCK / RED_COLS)                    // 4 waves
#define RED_BLOCKS (D / RED_COLS)                      // 128
#define CHUNKS_PER_SEG (NCHUNK / RED_SEGS)             // 64
#define STEPS_PER_SEG (T_STEPS / RED_SEGS)             // 25

// Kernel 1: partial column-dot-products over a 32-row chunk + partial sum(|W|).
// grid = (COLBLOCKS, NCHUNK) = (8, 256) = 2048 blocks (exactly co-resident).
// x read via wave-uniform scalar loads (s_load, K$); no LDS, no barrier.
__global__ void __launch_bounds__(BLOCK)
k_partial(const float* __restrict__ x, const float* __restrict__ W,
          float* __restrict__ ws_drive, float* __restrict__ ws_abs) {
    const int chunk = blockIdx.y;
    const int row0  = chunk * ROWS_PER_CHUNK;
    const int j0 = (blockIdx.x * BLOCK + threadIdx.x) * COLS_PER_THREAD;

    float ax = 0.f, ay = 0.f, az = 0.f, aw = 0.f;
    float asum = 0.f;
    #pragma unroll 8
    for (int i = 0; i < ROWS_PER_CHUNK; ++i) {
        const float xv = x[row0 + i];   // uniform -> s_load, K$-cached
        const float4 w = *reinterpret_cast<const float4*>(
            &W[(size_t)(row0 + i) * D + j0]);
        ax = fmaf(xv, w.x, ax);
        ay = fmaf(xv, w.y, ay);
        az = fmaf(xv, w.z, az);
        aw = fmaf(xv, w.w, aw);
        asum += fabsf(w.x) + fabsf(w.y) + fabsf(w.z) + fabsf(w.w);
    }

    float4 acc; acc.x = ax; acc.y = ay; acc.z = az; acc.w = aw;
    *reinterpret_cast<float4*>(&ws_drive[(size_t)chunk * D + j0]) = acc;

    // per-wave butterfly reduce of |W| partial (register-only, no barriers)
    #pragma unroll
    for (int off = 32; off > 0; off >>= 1)
        asum += __shfl_down(asum, off, 64);
    if ((threadIdx.x & 63) == 0)
        ws_abs[(chunk * COLBLOCKS + blockIdx.x) * WAVES + (threadIdx.x >> 6)] = asum;
}

// Kernel 2 (fused): reduce ws_drive -> drive for 64 cols, then simulate.
// grid = RED_BLOCKS + 1 = 129, block = 256 = 4 waves.
// Wave `seg` sums a 64-chunk segment (256 B wave loads), LDS-combine, then
// warms up seg*25 steps in registers and stores its 25 timesteps.
// Block 128 reduces ws_abs -> activity scalar at out[2*T*D].
__global__ void __launch_bounds__(BLOCK)
k_fused(const float* __restrict__ ws_drive, const float* __restrict__ ws_abs,
        const float* __restrict__ pot0, float* __restrict__ out) {
    if (blockIdx.x == RED_BLOCKS) {
        __shared__ float red[BLOCK];
        float s = 0.f;
        for (int i = threadIdx.x; i < NABS; i += BLOCK) s += ws_abs[i];
        red[threadIdx.x] = s;
        __syncthreads();
        for (int st = BLOCK / 2; st > 0; st >>= 1) {
            if (threadIdx.x < st) red[threadIdx.x] += red[threadIdx.x + st];
            __syncthreads();
        }
        if (threadIdx.x == 0)
            out[(size_t)2 * T_STEPS * D] = red[0] / ((float)D * (float)D);
        return;
    }

    __shared__ float part[RED_SEGS][RED_COLS];
    const int col = threadIdx.x & (RED_COLS - 1);
    const int seg = threadIdx.x >> 6;                  // wave id, 0..3
    const int j   = blockIdx.x * RED_COLS + col;

    // each wave sums a 64-chunk segment for its column (256 B/wave loads)
    float s = 0.f;
    const int c0 = seg * CHUNKS_PER_SEG;
    #pragma unroll 8
    for (int cc = 0; cc < CHUNKS_PER_SEG; ++cc)
        s += ws_drive[(size_t)(c0 + cc) * D + j];
    part[seg][col] = s;
    __syncthreads();

    const float d = part[0][col] + part[1][col] + part[2][col] + part[3][col];
    float p = pot0[j];

    // warm up to this wave's time slice (register-only)
    const int t0 = seg * STEPS_PER_SEG;
    for (int t = 0; t < t0; ++t) {
        p += d;
        p = (p >= SPIKE_THR) ? 0.f : p;
    }

    float* __restrict__ spikes = out;
    float* __restrict__ pots   = out + (size_t)T_STEPS * D;

    #pragma unroll
    for (int s2 = 0; s2 < STEPS_PER_SEG; ++s2) {
        const int t = t0 + s2;
        p += d;
        const float sp = (p >= SPIKE_THR) ? 1.f : 0.f;
        p *= (1.f - sp);
        spikes[(size_t)t * D + j] = sp;
        pots[(size_t)t * D + j]   = p;
    }
}

extern "C" void kernel_launch(void* const* d_in, const int* in_sizes, int n_in,
                              void* d_out, int out_size, void* d_ws, size_t ws_size,
                              hipStream_t stream) {
    const float* x   = (const float*)d_in[0];
    const float* W   = (const float*)d_in[1];
    const float* mp0 = (const float*)d_in[2];
    float* out = (float*)d_out;

    float* ws_drive = (float*)d_ws;                       // NCHUNK*D floats = 8 MiB
    float* ws_abs   = ws_drive + (size_t)NCHUNK * D;      // NABS floats

    dim3 g1(COLBLOCKS, NCHUNK);
    k_partial<<<g1, BLOCK, 0, stream>>>(x, W, ws_drive, ws_abs);
    k_fused<<<RED_BLOCKS + 1, BLOCK, 0, stream>>>(ws_drive, ws_abs, mp0, out);
}